// Round 9
// baseline (114.203 us; speedup 1.0000x reference)
//
#include <hip/hip_runtime.h>
#include <hip/hip_bf16.h>

#define L 256
#define DH 512
#define NBLK 256
#define NTHR 1024
#define MAT 262144
#define NPH 3
#define AGT __HIP_MEMORY_SCOPE_AGENT

typedef __attribute__((ext_vector_type(8))) short bf16x8;
typedef __attribute__((ext_vector_type(4))) float f32x4;
typedef unsigned long long u64;

static __device__ __forceinline__ ushort f2b(float v) {
  __hip_bfloat16 h = __float2bfloat16(v);
  return *(ushort*)&h;
}
// Write-through agent-scope stores -> coherent Infinity Cache. Consumers
// (post-barrier, first touch per XCD) use PLAIN cached loads.
static __device__ __forceinline__ void cstf(float* p, float v) {
  __hip_atomic_store(p, v, __ATOMIC_RELAXED, AGT);
}
static __device__ __forceinline__ void csth(ushort* p, ushort v) {
  __hip_atomic_store(p, v, __ATOMIC_RELAXED, AGT);
}
static __device__ __forceinline__ void cst8(void* p, u64 v) {
  __hip_atomic_store((u64*)p, v, __ATOMIC_RELAXED, AGT);
}

struct PARAMS {
  const float *x, *fcw, *w1, *w2, *wf1, *wf2;
  const float *fcb, *b1, *b2, *bl, *bf;
  float *out, *rep, *g1, *hsc, *dr;
  ushort *xb, *repb, *fcwt, *w1t, *w2t, *wf1t, *wf2t;
  int *bar;
};

// zero-RMW grid barrier (r8): parallel flag stores; block 0 polls concurrently.
static __device__ __forceinline__ void gridbar(int* bar, int ph) {
  __syncthreads();
  int* flags = bar + ph * 4096;
  int* rel   = bar + NPH * 4096 + ph * 16;
  const int tid = threadIdx.x;
  if (blockIdx.x == 0) {
    if (tid > 0 && tid < NBLK) {
      while (!__hip_atomic_load(flags + tid * 16, __ATOMIC_RELAXED, AGT))
        __builtin_amdgcn_s_sleep(1);
    }
    __syncthreads();
    if (tid == 0)
      __hip_atomic_store(rel, 1, __ATOMIC_RELAXED, AGT);
  } else if (tid == 0) {
    __hip_atomic_store(flags + blockIdx.x * 16, 1, __ATOMIC_RELAXED, AGT);
    while (!__hip_atomic_load(rel, __ATOMIC_RELAXED, AGT))
      __builtin_amdgcn_s_sleep(1);
  }
  __syncthreads();
}

// 16x16 tile, K=512, one wave; plain cached loads (both operands [row][K] bf16)
static __device__ __forceinline__ void gemm16(const ushort* __restrict__ A,
    const ushort* __restrict__ Bt, int m0, int n0, f32x4& acc)
{
  const int l  = threadIdx.x & 63;
  const int fr = l & 15, kg = (l >> 4) << 3;
  const ushort* pa = A  + (size_t)(m0 + fr) * DH + kg;
  const ushort* pb = Bt + (size_t)(n0 + fr) * DH + kg;
#pragma unroll 8
  for (int kt = 0; kt < DH; kt += 32)
    acc = __builtin_amdgcn_mfma_f32_16x16x32_bf16(*(const bf16x8*)(pa + kt),
                                                  *(const bf16x8*)(pb + kt), acc, 0, 0, 0);
}

// 16x32 job: one A-frag stream, two B-tiles
static __device__ __forceinline__ void gemm16x2(const ushort* __restrict__ A,
    const ushort* __restrict__ Bt, int m0, int n0, f32x4& acc0, f32x4& acc1)
{
  const int l  = threadIdx.x & 63;
  const int fr = l & 15, kg = (l >> 4) << 3;
  const ushort* pa  = A  + (size_t)(m0 + fr) * DH + kg;
  const ushort* pb0 = Bt + (size_t)(n0 + fr) * DH + kg;
  const ushort* pb1 = pb0 + 16 * DH;
#pragma unroll 4
  for (int kt = 0; kt < DH; kt += 32) {
    const bf16x8 a  = *(const bf16x8*)(pa + kt);
    acc0 = __builtin_amdgcn_mfma_f32_16x16x32_bf16(a, *(const bf16x8*)(pb0 + kt), acc0, 0, 0, 0);
    acc1 = __builtin_amdgcn_mfma_f32_16x16x32_bf16(a, *(const bf16x8*)(pb1 + kt), acc1, 0, 0, 0);
  }
}

// scatter-read transpose+cast of one 256-element wave-job: dst[n][k]=bf16(src[k][n])
static __device__ __forceinline__ void tconv(const float* __restrict__ src,
                                             ushort* __restrict__ dst, int rem)
{
  const int lane = threadIdx.x & 63;
#pragma unroll
  for (int i = 0; i < 4; ++i) {
    const int e = rem * 256 + i * 64 + lane;
    const int n = e >> 9, k = e & 511;
    csth(&dst[(size_t)n * DH + k], f2b(src[(size_t)k * DH + n]));
  }
}

__global__ __launch_bounds__(NTHR, 4) void mega(PARAMS p)
{
  const int tid  = threadIdx.x;
  const int bid  = blockIdx.x;
  const int widx = tid >> 6;
  const int lane = tid & 63;
  const int fr   = lane & 15, rg = (lane >> 4) << 2;
  const float c1  = 0.57707801635558534f;   // 2*log2(e)/C
  const float Ac  = 7.2134752044448169f;    // C*log2(e)
  const float Bc  = 14.426950408889634f;    // 2C*log2(e)
  const float l2e = 1.4426950408889634f;

  __shared__ float tr[32][33];
  __shared__ float attn_s[2][DH];

  // ---------- P0: cast x -> xb ; transpose+cast fcw -> fcwt ----------
  {
    const int gid = bid * NTHR + tid;
    if (gid < 65536) {
      const float4 v = ((const float4*)p.x)[gid];
      union { ushort4 s; u64 q; } o;
      o.s.x = f2b(v.x); o.s.y = f2b(v.y); o.s.z = f2b(v.z); o.s.w = f2b(v.w);
      cst8((ushort4*)p.xb + gid, o.q);
    }
    const int tx = tid & 31, ty = tid >> 5;          // ty in [0,32)
    const int r0 = (bid >> 4) << 5, c0 = (bid & 15) << 5;
    tr[ty][tx] = p.fcw[(size_t)(r0 + ty) * DH + c0 + tx];
    __syncthreads();
    csth(&p.fcwt[(size_t)(c0 + ty) * DH + r0 + tx], f2b(tr[tx][ty]));
  }
  gridbar(p.bar, 0);

  // ---------- P1: rep = elu(x@fc_w+fc_b) [1024 jobs] ; idle waves: w1t/w2t/wf1t ----------
  {
    const int wv = widx * NBLK + bid;                // 0..4095
    if (wv < 1024) {
      const int m0 = (wv >> 5) << 4, n0 = (wv & 31) << 4;
      f32x4 acc = {};
      gemm16(p.xb, p.fcwt, m0, n0, acc);
      const int col = n0 + fr;
      const float bv = p.fcb[col];
#pragma unroll
      for (int r = 0; r < 4; ++r) {
        float v = acc[r] + bv;
        v = v > 0.0f ? v : (__builtin_amdgcn_exp2f(v * l2e) - 1.0f);
        const size_t idx = (size_t)(m0 + rg + r) * DH + col;
        cstf(p.rep + idx, v);
        csth(p.repb + idx, f2b(v));
        cstf(p.dr + idx * 2 + 1, v);
      }
    } else {
      const int wv2 = wv - 1024, z = wv2 >> 10, rem = wv2 & 1023;
      tconv(z == 0 ? p.w1 : (z == 1 ? p.w2 : p.wf1),
            z == 0 ? p.w1t : (z == 1 ? p.w2t : p.wf1t), rem);
    }
  }
  gridbar(p.bar, 1);

  // ---------- P2: dr.x=2^(dep'*c1) ; hsc=2^(head'*c1) ; g1=rep@wf1 ; idle: wf2t ----------
  {
    const int wv = widx * NBLK + bid;
    if (wv < 1536) {
      const int z = wv >> 9, rem = wv & 511;
      const int m0 = (rem >> 4) << 4, n0 = (rem & 15) << 5;
      const ushort* Bt = (z == 0) ? p.w1t : (z == 1) ? p.w2t : p.wf1t;
      f32x4 acc[2] = {};
      gemm16x2(p.repb, Bt, m0, n0, acc[0], acc[1]);
#pragma unroll
      for (int f = 0; f < 2; ++f) {
        const int col = n0 + f * 16 + fr;
#pragma unroll
        for (int r = 0; r < 4; ++r) {
          const size_t idx = (size_t)(m0 + rg + r) * DH + col;
          if (z == 0)
            cstf(p.dr + idx * 2,
                 __builtin_amdgcn_exp2f((acc[f][r] + p.b1[col] + p.bl[col]) * c1));
          else if (z == 1)
            cstf(p.hsc + idx,
                 __builtin_amdgcn_exp2f((acc[f][r] + p.b2[col]) * c1));
          else
            cstf(p.g1 + idx, acc[f][r]);
        }
      }
    } else if (wv < 2560) {
      tconv(p.wf2, p.wf2t, wv - 1536);
    }
  }
  gridbar(p.bar, 2);

  // ---------- P3': attention (1 row/thread, unroll-8) + fused g2/gate/out ----------
  {
    const int b = bid >> 7, pp = bid & 127;
    const int s = tid >> 9, h = tid & 511;
    const int irow = s ? (255 - pp) : pp;            // wave-uniform
    const float2* drp = (const float2*)p.dr + (size_t)b * L * DH + h;
    float sa, aa = 0.0f;
    if (irow == 255) {                               // fully-masked row: uniform 1/256
      sa = 256.0f;
      for (int j = 0; j < 256; j += 8) {
        float2 v[8];
#pragma unroll
        for (int u = 0; u < 8; ++u) v[u] = drp[(size_t)(j + u) * DH];
#pragma unroll
        for (int u = 0; u < 8; ++u) aa += v[u].y;
      }
    } else {
      const float Eh = p.hsc[((size_t)b * L + irow) * DH + h];
      sa = 0.0f;
      int j = irow + 1;
      for (; j + 8 <= 256; j += 8) {
        float2 v[8];
#pragma unroll
        for (int u = 0; u < 8; ++u) v[u] = drp[(size_t)(j + u) * DH];
#pragma unroll
        for (int u = 0; u < 8; ++u) {
          const float E = v[u].x * Eh;
          const float w = __builtin_amdgcn_exp2f(
              fmaf(-Bc, __builtin_amdgcn_rcpf(E + 1.0f), Ac));
          sa += w; aa = fmaf(w, v[u].y, aa);
        }
      }
      for (; j < 256; ++j) {
        const float2 v = drp[(size_t)j * DH];
        const float E = v.x * Eh;
        const float w = __builtin_amdgcn_exp2f(
            fmaf(-Bc, __builtin_amdgcn_rcpf(E + 1.0f), Ac));
        sa += w; aa = fmaf(w, v.y, aa);
      }
    }
    attn_s[s][h] = aa * __builtin_amdgcn_rcpf(sa);
    __syncthreads();

    // fused P4 for this block's two rows: g2 = attn_row @ wf2t^T (row n of wf2t)
    const int n = h;
    const float* arow = attn_s[s];
    const ushort* wrow = p.wf2t + (size_t)n * DH;
    float g2 = 0.0f;
#pragma unroll 4
    for (int hh = 0; hh < DH; hh += 8) {
      const uint4 q = *(const uint4*)(wrow + hh);
      const float4 a0 = *(const float4*)(arow + hh);
      const float4 a1 = *(const float4*)(arow + hh + 4);
      g2 = fmaf(__uint_as_float(q.x << 16),          a0.x, g2);
      g2 = fmaf(__uint_as_float(q.x & 0xffff0000u),  a0.y, g2);
      g2 = fmaf(__uint_as_float(q.y << 16),          a0.z, g2);
      g2 = fmaf(__uint_as_float(q.y & 0xffff0000u),  a0.w, g2);
      g2 = fmaf(__uint_as_float(q.z << 16),          a1.x, g2);
      g2 = fmaf(__uint_as_float(q.z & 0xffff0000u),  a1.y, g2);
      g2 = fmaf(__uint_as_float(q.w << 16),          a1.z, g2);
      g2 = fmaf(__uint_as_float(q.w & 0xffff0000u),  a1.w, g2);
    }
    const size_t ridx = ((size_t)b * L + irow) * DH + n;
    const float sg = p.g1[ridx] + g2 + p.bf[n];
    const float gate = __builtin_amdgcn_rcpf(
        1.0f + __builtin_amdgcn_exp2f(-sg * l2e));
    p.out[ridx] = gate * p.rep[ridx] + (1.0f - gate) * arow[n];
  }
}

extern "C" void kernel_launch(void* const* d_in, const int* in_sizes, int n_in,
                              void* d_out, int out_size, void* d_ws, size_t ws_size,
                              hipStream_t stream)
{
  PARAMS p;
  p.x   = (const float*)d_in[0];
  p.fcw = (const float*)d_in[1];
  p.fcb = (const float*)d_in[2];
  p.w1  = (const float*)d_in[3];
  p.b1  = (const float*)d_in[4];
  p.w2  = (const float*)d_in[5];
  p.b2  = (const float*)d_in[6];
  p.bl  = (const float*)d_in[7];
  p.wf1 = (const float*)d_in[8];
  p.wf2 = (const float*)d_in[9];
  p.bf  = (const float*)d_in[10];
  p.out = (float*)d_out;

  float* ws = (float*)d_ws;
  p.rep  = ws;                 // MAT
  p.g1   = ws + 1 * MAT;
  p.hsc  = ws + 2 * MAT;       // E_h = 2^(head'*c1)
  p.dr   = ws + 3 * MAT;       // 2*MAT: float2 {E_d, rep}
  ushort* ub = (ushort*)(ws + 5 * MAT);
  p.xb    = ub + 0 * MAT;
  p.repb  = ub + 1 * MAT;
  p.fcwt  = ub + 2 * MAT;
  p.w1t   = ub + 3 * MAT;
  p.w2t   = ub + 4 * MAT;
  p.wf1t  = ub + 5 * MAT;
  p.wf2t  = ub + 6 * MAT;
  p.bar   = (int*)(ws + 9 * MAT);

  hipMemsetAsync(p.bar, 0, (NPH * 4096 + NPH * 16) * sizeof(int), stream);
  void* args[] = { &p };
  hipLaunchCooperativeKernel((void*)mega, dim3(NBLK), dim3(NTHR), args, 0, stream);
}

// Round 10
// 95.308 us; speedup vs baseline: 1.1982x; 1.1982x over previous
//
#include <hip/hip_runtime.h>
#include <hip/hip_bf16.h>

#define L 256
#define DH 512
#define MAT 262144

typedef __attribute__((ext_vector_type(8))) short bf16x8;
typedef __attribute__((ext_vector_type(4))) float f32x4;
typedef unsigned long long u64;

static __device__ __forceinline__ ushort f2b(float v) {
  __hip_bfloat16 h = __float2bfloat16(v);
  return *(ushort*)&h;
}

#define C1F 0.57707801635558534f    // 2*log2(e)/C
#define ACF 7.2134752044448169f     // C*log2(e)
#define BCF 14.426950408889634f     // 2C*log2(e)
#define L2E 1.4426950408889634f

// ---------- D1: cast x -> xb ; transpose+cast 5 weights to [N][K] bf16 ----------
__global__ __launch_bounds__(256) void k_conv(
    const float* __restrict__ x,
    const float* __restrict__ fcw, const float* __restrict__ w1,
    const float* __restrict__ w2, const float* __restrict__ wf1,
    const float* __restrict__ wf2,
    ushort* __restrict__ xb,
    ushort* __restrict__ fcwt, ushort* __restrict__ w1t,
    ushort* __restrict__ w2t, ushort* __restrict__ wf1t,
    ushort* __restrict__ wf2t)
{
  const int z = blockIdx.z;
  const float* src; ushort* dst;
  switch (z) {
    case 0: src = fcw; dst = fcwt; break;
    case 1: src = w1;  dst = w1t;  break;
    case 2: src = w2;  dst = w2t;  break;
    case 3: src = wf1; dst = wf1t; break;
    case 4: src = wf2; dst = wf2t; break;
    default: src = x;  dst = xb;   break;
  }
  const int tx = threadIdx.x & 31, ty = threadIdx.x >> 5;
  const int c0 = blockIdx.x * 32, r0 = blockIdx.y * 32;
  if (z == 5) {
#pragma unroll
    for (int r = 0; r < 4; ++r) {
      const int row = r0 + ty + 8 * r;
      dst[(size_t)row * DH + c0 + tx] = f2b(src[(size_t)row * DH + c0 + tx]);
    }
  } else {
    __shared__ float t[32][33];
#pragma unroll
    for (int r = 0; r < 4; ++r)
      t[ty + 8 * r][tx] = src[(size_t)(r0 + ty + 8 * r) * DH + c0 + tx];
    __syncthreads();
#pragma unroll
    for (int r = 0; r < 4; ++r)
      dst[(size_t)(c0 + ty + 8 * r) * DH + r0 + tx] = f2b(t[tx][ty + 8 * r]);
  }
}

// 16x16 tile, K=512, one wave; both operands [row][K] bf16
static __device__ __forceinline__ void gemm16(const ushort* __restrict__ A,
    const ushort* __restrict__ Bt, int m0, int n0, f32x4& acc)
{
  const int l  = threadIdx.x & 63;
  const int fr = l & 15, kg = (l >> 4) << 3;
  const ushort* pa = A  + (size_t)(m0 + fr) * DH + kg;
  const ushort* pb = Bt + (size_t)(n0 + fr) * DH + kg;
#pragma unroll 8
  for (int kt = 0; kt < DH; kt += 32)
    acc = __builtin_amdgcn_mfma_f32_16x16x32_bf16(*(const bf16x8*)(pa + kt),
                                                  *(const bf16x8*)(pb + kt), acc, 0, 0, 0);
}

// 16x32 job: one A-frag stream, two B-tiles
static __device__ __forceinline__ void gemm16x2(const ushort* __restrict__ A,
    const ushort* __restrict__ Bt, int m0, int n0, f32x4& acc0, f32x4& acc1)
{
  const int l  = threadIdx.x & 63;
  const int fr = l & 15, kg = (l >> 4) << 3;
  const ushort* pa  = A  + (size_t)(m0 + fr) * DH + kg;
  const ushort* pb0 = Bt + (size_t)(n0 + fr) * DH + kg;
  const ushort* pb1 = pb0 + 16 * DH;
#pragma unroll 4
  for (int kt = 0; kt < DH; kt += 32) {
    const bf16x8 a  = *(const bf16x8*)(pa + kt);
    acc0 = __builtin_amdgcn_mfma_f32_16x16x32_bf16(a, *(const bf16x8*)(pb0 + kt), acc0, 0, 0, 0);
    acc1 = __builtin_amdgcn_mfma_f32_16x16x32_bf16(a, *(const bf16x8*)(pb1 + kt), acc1, 0, 0, 0);
  }
}

// ---------- D2: rep = elu(x@fc_w + fc_b); writes rep f32, repb bf16, dr.y ----------
__global__ __launch_bounds__(512) void k_rep(const ushort* __restrict__ xb,
    const ushort* __restrict__ fcwt, const float* __restrict__ fcb,
    float* __restrict__ rep, ushort* __restrict__ repb, float* __restrict__ dr)
{
  const int wv = blockIdx.x * 8 + (threadIdx.x >> 6);   // 0..1023
  const int lane = threadIdx.x & 63;
  const int fr = lane & 15, rg = (lane >> 4) << 2;
  const int m0 = (wv >> 5) << 4, n0 = (wv & 31) << 4;
  f32x4 acc = {};
  gemm16(xb, fcwt, m0, n0, acc);
  const int col = n0 + fr;
  const float bv = fcb[col];
#pragma unroll
  for (int r = 0; r < 4; ++r) {
    float v = acc[r] + bv;
    v = v > 0.0f ? v : (__builtin_amdgcn_exp2f(v * L2E) - 1.0f);
    const size_t idx = (size_t)(m0 + rg + r) * DH + col;
    rep[idx]  = v;
    repb[idx] = f2b(v);
    dr[idx * 2 + 1] = v;
  }
}

// ---------- D3: dr.x = 2^((rep@w1+b1+bl)*c1) ; hsc = 2^((rep@w2+b2)*c1) ; g1 = rep@wf1 ----------
__global__ __launch_bounds__(512) void k_triple(const ushort* __restrict__ repb,
    const ushort* __restrict__ w1t, const float* __restrict__ b1,
    const ushort* __restrict__ w2t, const float* __restrict__ b2,
    const ushort* __restrict__ wf1t, const float* __restrict__ bl,
    float* __restrict__ dr, float* __restrict__ hsc, float* __restrict__ g1)
{
  const int wv = blockIdx.x * 8 + (threadIdx.x >> 6);   // 0..1535
  const int lane = threadIdx.x & 63;
  const int fr = lane & 15, rg = (lane >> 4) << 2;
  const int z = wv >> 9, rem = wv & 511;
  const int m0 = (rem >> 4) << 4, n0 = (rem & 15) << 5;
  const ushort* Bt = (z == 0) ? w1t : (z == 1) ? w2t : wf1t;
  f32x4 acc[2] = {};
  gemm16x2(repb, Bt, m0, n0, acc[0], acc[1]);
#pragma unroll
  for (int f = 0; f < 2; ++f) {
    const int col = n0 + f * 16 + fr;
#pragma unroll
    for (int r = 0; r < 4; ++r) {
      const size_t idx = (size_t)(m0 + rg + r) * DH + col;
      if (z == 0)
        dr[idx * 2] = __builtin_amdgcn_exp2f((acc[f][r] + b1[col] + bl[col]) * C1F);
      else if (z == 1)
        hsc[idx] = __builtin_amdgcn_exp2f((acc[f][r] + b2[col]) * C1F);
      else
        g1[idx] = acc[f][r];
    }
  }
}

// ---------- D4: attention (rows {pp, 255-pp}, 1 row/thread-half) + fused gate/out ----------
__global__ __launch_bounds__(1024) void k_attn_final(
    const float* __restrict__ dr, const float* __restrict__ hsc,
    const float* __restrict__ g1, const float* __restrict__ rep,
    const ushort* __restrict__ wf2t, const float* __restrict__ bf,
    float* __restrict__ out)
{
  __shared__ float attn_s[2][DH];
  const int bid = blockIdx.x;
  const int b = bid >> 7, pp = bid & 127;
  const int s = threadIdx.x >> 9, h = threadIdx.x & 511;
  const int irow = s ? (255 - pp) : pp;                // wave-uniform
  const float2* drp = (const float2*)dr + (size_t)b * L * DH + h;
  float sa, aa = 0.0f;
  if (irow == 255) {                                   // fully-masked row: uniform 1/256
    sa = 256.0f;
    for (int j = 0; j < 256; j += 8) {
      float2 v[8];
#pragma unroll
      for (int u = 0; u < 8; ++u) v[u] = drp[(size_t)(j + u) * DH];
#pragma unroll
      for (int u = 0; u < 8; ++u) aa += v[u].y;
    }
  } else {
    const float Eh = hsc[((size_t)b * L + irow) * DH + h];
    sa = 0.0f;
    int j = irow + 1;
    for (; j + 8 <= 256; j += 8) {
      float2 v[8];
#pragma unroll
      for (int u = 0; u < 8; ++u) v[u] = drp[(size_t)(j + u) * DH];
#pragma unroll
      for (int u = 0; u < 8; ++u) {
        const float E = v[u].x * Eh;
        const float w = __builtin_amdgcn_exp2f(
            fmaf(-BCF, __builtin_amdgcn_rcpf(E + 1.0f), ACF));
        sa += w; aa = fmaf(w, v[u].y, aa);
      }
    }
    for (; j < 256; ++j) {
      const float2 v = drp[(size_t)j * DH];
      const float E = v.x * Eh;
      const float w = __builtin_amdgcn_exp2f(
          fmaf(-BCF, __builtin_amdgcn_rcpf(E + 1.0f), ACF));
      sa += w; aa = fmaf(w, v.y, aa);
    }
  }
  attn_s[s][h] = aa * __builtin_amdgcn_rcpf(sa);
  __syncthreads();

  // fused gate: g2[n] = attn_row . wf2t[n][:]
  const int n = h;
  const float* arow = attn_s[s];
  const ushort* wrow = wf2t + (size_t)n * DH;
  float g2 = 0.0f;
#pragma unroll 4
  for (int hh = 0; hh < DH; hh += 8) {
    const uint4 q = *(const uint4*)(wrow + hh);
    const float4 a0 = *(const float4*)(arow + hh);
    const float4 a1 = *(const float4*)(arow + hh + 4);
    g2 = fmaf(__uint_as_float(q.x << 16),          a0.x, g2);
    g2 = fmaf(__uint_as_float(q.x & 0xffff0000u),  a0.y, g2);
    g2 = fmaf(__uint_as_float(q.y << 16),          a0.z, g2);
    g2 = fmaf(__uint_as_float(q.y & 0xffff0000u),  a0.w, g2);
    g2 = fmaf(__uint_as_float(q.z << 16),          a1.x, g2);
    g2 = fmaf(__uint_as_float(q.z & 0xffff0000u),  a1.y, g2);
    g2 = fmaf(__uint_as_float(q.w << 16),          a1.z, g2);
    g2 = fmaf(__uint_as_float(q.w & 0xffff0000u),  a1.w, g2);
  }
  const size_t ridx = ((size_t)b * L + irow) * DH + n;
  const float sg = g1[ridx] + g2 + bf[n];
  const float gate = __builtin_amdgcn_rcpf(
      1.0f + __builtin_amdgcn_exp2f(-sg * L2E));
  out[ridx] = gate * rep[ridx] + (1.0f - gate) * arow[n];
}

extern "C" void kernel_launch(void* const* d_in, const int* in_sizes, int n_in,
                              void* d_out, int out_size, void* d_ws, size_t ws_size,
                              hipStream_t stream)
{
  const float* x   = (const float*)d_in[0];
  const float* fcw = (const float*)d_in[1];
  const float* fcb = (const float*)d_in[2];
  const float* w1  = (const float*)d_in[3];
  const float* b1  = (const float*)d_in[4];
  const float* w2  = (const float*)d_in[5];
  const float* b2  = (const float*)d_in[6];
  const float* bl  = (const float*)d_in[7];
  const float* wf1 = (const float*)d_in[8];
  const float* wf2 = (const float*)d_in[9];
  const float* bf  = (const float*)d_in[10];
  float* out = (float*)d_out;

  float* ws = (float*)d_ws;
  float* rep = ws;                 // MAT
  float* g1  = ws + 1 * MAT;
  float* hsc = ws + 2 * MAT;       // E_h = 2^(head'*c1)
  float* dr  = ws + 3 * MAT;       // 2*MAT: float2 {E_d, rep}
  ushort* ub = (ushort*)(ws + 5 * MAT);
  ushort* xb   = ub + 0 * MAT;
  ushort* repb = ub + 1 * MAT;
  ushort* fcwt = ub + 2 * MAT;
  ushort* w1t  = ub + 3 * MAT;
  ushort* w2t  = ub + 4 * MAT;
  ushort* wf1t = ub + 5 * MAT;
  ushort* wf2t = ub + 6 * MAT;

  k_conv<<<dim3(16, 16, 6), dim3(256), 0, stream>>>(x, fcw, w1, w2, wf1, wf2,
                                                    xb, fcwt, w1t, w2t, wf1t, wf2t);
  k_rep<<<dim3(128), dim3(512), 0, stream>>>(xb, fcwt, fcb, rep, repb, dr);
  k_triple<<<dim3(192), dim3(512), 0, stream>>>(repb, w1t, b1, w2t, b2, wf1t, bl,
                                                dr, hsc, g1);
  k_attn_final<<<dim3(256), dim3(1024), 0, stream>>>(dr, hsc, g1, rep, wf2t, bf, out);
}

// Round 11
// 70.456 us; speedup vs baseline: 1.6209x; 1.3527x over previous
//
#include <hip/hip_runtime.h>
#include <hip/hip_bf16.h>

#define L 256
#define DH 512
#define MAT 262144

typedef __attribute__((ext_vector_type(8))) short bf16x8;
typedef __attribute__((ext_vector_type(4))) float f32x4;
typedef unsigned long long u64;

static __device__ __forceinline__ ushort f2b(float v) {
  __hip_bfloat16 h = __float2bfloat16(v);
  return *(ushort*)&h;
}

#define C1F 0.57707801635558534f    // 2*log2(e)/C
#define ACF 7.2134752044448169f     // C*log2(e)
#define BCF 14.426950408889634f     // 2C*log2(e)
#define L2E 1.4426950408889634f

// ---------- D1: cast x -> xb ; transpose+cast 5 weights to [N][K] bf16 ----------
__global__ __launch_bounds__(256) void k_conv(
    const float* __restrict__ x,
    const float* __restrict__ fcw, const float* __restrict__ w1,
    const float* __restrict__ w2, const float* __restrict__ wf1,
    const float* __restrict__ wf2,
    ushort* __restrict__ xb,
    ushort* __restrict__ fcwt, ushort* __restrict__ w1t,
    ushort* __restrict__ w2t, ushort* __restrict__ wf1t,
    ushort* __restrict__ wf2t)
{
  const int z = blockIdx.z;
  const float* src; ushort* dst;
  switch (z) {
    case 0: src = fcw; dst = fcwt; break;
    case 1: src = w1;  dst = w1t;  break;
    case 2: src = w2;  dst = w2t;  break;
    case 3: src = wf1; dst = wf1t; break;
    case 4: src = wf2; dst = wf2t; break;
    default: src = x;  dst = xb;   break;
  }
  const int tx = threadIdx.x & 31, ty = threadIdx.x >> 5;
  const int c0 = blockIdx.x * 32, r0 = blockIdx.y * 32;
  if (z == 5) {
#pragma unroll
    for (int r = 0; r < 4; ++r) {
      const int row = r0 + ty + 8 * r;
      dst[(size_t)row * DH + c0 + tx] = f2b(src[(size_t)row * DH + c0 + tx]);
    }
  } else {
    __shared__ float t[32][33];
#pragma unroll
    for (int r = 0; r < 4; ++r)
      t[ty + 8 * r][tx] = src[(size_t)(r0 + ty + 8 * r) * DH + c0 + tx];
    __syncthreads();
#pragma unroll
    for (int r = 0; r < 4; ++r)
      dst[(size_t)(c0 + ty + 8 * r) * DH + r0 + tx] = f2b(t[tx][ty + 8 * r]);
  }
}

// 16x16 tile, K=512, one wave; both operands [row][K] bf16
static __device__ __forceinline__ void gemm16(const ushort* __restrict__ A,
    const ushort* __restrict__ Bt, int m0, int n0, f32x4& acc)
{
  const int l  = threadIdx.x & 63;
  const int fr = l & 15, kg = (l >> 4) << 3;
  const ushort* pa = A  + (size_t)(m0 + fr) * DH + kg;
  const ushort* pb = Bt + (size_t)(n0 + fr) * DH + kg;
#pragma unroll 8
  for (int kt = 0; kt < DH; kt += 32)
    acc = __builtin_amdgcn_mfma_f32_16x16x32_bf16(*(const bf16x8*)(pa + kt),
                                                  *(const bf16x8*)(pb + kt), acc, 0, 0, 0);
}

// 16x32 job: one A-frag stream, two B-tiles
static __device__ __forceinline__ void gemm16x2(const ushort* __restrict__ A,
    const ushort* __restrict__ Bt, int m0, int n0, f32x4& acc0, f32x4& acc1)
{
  const int l  = threadIdx.x & 63;
  const int fr = l & 15, kg = (l >> 4) << 3;
  const ushort* pa  = A  + (size_t)(m0 + fr) * DH + kg;
  const ushort* pb0 = Bt + (size_t)(n0 + fr) * DH + kg;
  const ushort* pb1 = pb0 + 16 * DH;
#pragma unroll 4
  for (int kt = 0; kt < DH; kt += 32) {
    const bf16x8 a  = *(const bf16x8*)(pa + kt);
    acc0 = __builtin_amdgcn_mfma_f32_16x16x32_bf16(a, *(const bf16x8*)(pb0 + kt), acc0, 0, 0, 0);
    acc1 = __builtin_amdgcn_mfma_f32_16x16x32_bf16(a, *(const bf16x8*)(pb1 + kt), acc1, 0, 0, 0);
  }
}

// ---------- D2: rep = elu(x@fc_w + fc_b); writes rep f32, repb bf16, dr.y ----------
__global__ __launch_bounds__(512) void k_rep(const ushort* __restrict__ xb,
    const ushort* __restrict__ fcwt, const float* __restrict__ fcb,
    float* __restrict__ rep, ushort* __restrict__ repb, float* __restrict__ dr)
{
  const int wv = blockIdx.x * 8 + (threadIdx.x >> 6);   // 0..1023
  const int lane = threadIdx.x & 63;
  const int fr = lane & 15, rg = (lane >> 4) << 2;
  const int m0 = (wv >> 5) << 4, n0 = (wv & 31) << 4;
  f32x4 acc = {};
  gemm16(xb, fcwt, m0, n0, acc);
  const int col = n0 + fr;
  const float bv = fcb[col];
#pragma unroll
  for (int r = 0; r < 4; ++r) {
    float v = acc[r] + bv;
    v = v > 0.0f ? v : (__builtin_amdgcn_exp2f(v * L2E) - 1.0f);
    const size_t idx = (size_t)(m0 + rg + r) * DH + col;
    rep[idx]  = v;
    repb[idx] = f2b(v);
    dr[idx * 2 + 1] = v;
  }
}

// ---------- D3: dr.x = 2^((rep@w1+b1+bl)*c1) ; hsc = 2^((rep@w2+b2)*c1) ; g1 = rep@wf1 ----------
__global__ __launch_bounds__(512) void k_triple(const ushort* __restrict__ repb,
    const ushort* __restrict__ w1t, const float* __restrict__ b1,
    const ushort* __restrict__ w2t, const float* __restrict__ b2,
    const ushort* __restrict__ wf1t, const float* __restrict__ bl,
    float* __restrict__ dr, float* __restrict__ hsc, float* __restrict__ g1)
{
  const int wv = blockIdx.x * 8 + (threadIdx.x >> 6);   // 0..1535
  const int lane = threadIdx.x & 63;
  const int fr = lane & 15, rg = (lane >> 4) << 2;
  const int z = wv >> 9, rem = wv & 511;
  const int m0 = (rem >> 4) << 4, n0 = (rem & 15) << 5;
  const ushort* Bt = (z == 0) ? w1t : (z == 1) ? w2t : wf1t;
  f32x4 acc[2] = {};
  gemm16x2(repb, Bt, m0, n0, acc[0], acc[1]);
#pragma unroll
  for (int f = 0; f < 2; ++f) {
    const int col = n0 + f * 16 + fr;
#pragma unroll
    for (int r = 0; r < 4; ++r) {
      const size_t idx = (size_t)(m0 + rg + r) * DH + col;
      if (z == 0)
        dr[idx * 2] = __builtin_amdgcn_exp2f((acc[f][r] + b1[col] + bl[col]) * C1F);
      else if (z == 1)
        hsc[idx] = __builtin_amdgcn_exp2f((acc[f][r] + b2[col]) * C1F);
      else
        g1[idx] = acc[f][r];
    }
  }
}

// ---------- D4: LDS-broadcast attention. block = (h-tile of 4, b); thread (i, s) ----------
// Stage dr strip [256 j][4 h] into LDS; wave-uniform j-loop, same-address broadcast reads.
// w = 2^(Ac - Bc*rcp(E_d*E_h + 1)) masked j>i; row 255 fully masked -> uniform weights.
__global__ __launch_bounds__(1024) void k_attn(
    const float* __restrict__ dr, const float* __restrict__ hsc,
    ushort* __restrict__ attnb)
{
  __shared__ float2 sdr[256][4];
  const int hc = blockIdx.x, b = blockIdx.y;
  const int h0 = hc * 4;
  const int t = threadIdx.x;
  const int i = t & 255, s = t >> 8;
  {
    const int row = t >> 2, hh = t & 3;
    sdr[row][hh] = ((const float2*)dr)[((size_t)b * L + row) * DH + h0 + hh];
  }
  __syncthreads();
  const int h = h0 + s;
  const bool full = (i == 255);                 // fully-masked row -> uniform 1/256
  const float Eh = hsc[((size_t)b * L + i) * DH + h];
  const int i0 = i & 192;                       // wave-uniform (lanes cover i0..i0+63)
  const int jstart = (i0 == 192) ? 0 : i0;      // wave with row 255 needs full range
  float sa = 0.0f, aa = 0.0f;
  for (int j = jstart; j < 256; j += 8) {
    float2 v[8];
#pragma unroll
    for (int u = 0; u < 8; ++u) v[u] = sdr[j + u][s];
#pragma unroll
    for (int u = 0; u < 8; ++u) {
      const float E = v[u].x * Eh;
      float w = __builtin_amdgcn_exp2f(
          fmaf(-BCF, __builtin_amdgcn_rcpf(E + 1.0f), ACF));
      w = (j + u > i) ? w : 0.0f;
      w = full ? 1.0f : w;
      sa += w;
      aa = fmaf(w, v[u].y, aa);
    }
  }
  attnb[((size_t)b * L + i) * DH + h] = f2b(aa * __builtin_amdgcn_rcpf(sa));
}

// ---------- D5: g2 = attn@wf2 ; gate = sigmoid(g1+g2+bf) ; out = mix ----------
__global__ __launch_bounds__(512) void k_final(
    const ushort* __restrict__ attnb, const ushort* __restrict__ wf2t,
    const float* __restrict__ g1, const float* __restrict__ rep,
    const float* __restrict__ bf, float* __restrict__ out)
{
  const int wv = blockIdx.x * 8 + (threadIdx.x >> 6);   // 0..1023
  const int lane = threadIdx.x & 63;
  const int fr = lane & 15, rg = (lane >> 4) << 2;
  const int m0 = (wv >> 5) << 4, n0 = (wv & 31) << 4;
  f32x4 acc = {};
  gemm16(attnb, wf2t, m0, n0, acc);
  const int col = n0 + fr;
  const float bv = bf[col];
#pragma unroll
  for (int r = 0; r < 4; ++r) {
    const size_t idx = (size_t)(m0 + rg + r) * DH + col;
    const float sg = g1[idx] + acc[r] + bv;
    const float gate = __builtin_amdgcn_rcpf(
        1.0f + __builtin_amdgcn_exp2f(-sg * L2E));
    const float av = __uint_as_float((unsigned)attnb[idx] << 16);
    out[idx] = gate * rep[idx] + (1.0f - gate) * av;
  }
}

extern "C" void kernel_launch(void* const* d_in, const int* in_sizes, int n_in,
                              void* d_out, int out_size, void* d_ws, size_t ws_size,
                              hipStream_t stream)
{
  const float* x   = (const float*)d_in[0];
  const float* fcw = (const float*)d_in[1];
  const float* fcb = (const float*)d_in[2];
  const float* w1  = (const float*)d_in[3];
  const float* b1  = (const float*)d_in[4];
  const float* w2  = (const float*)d_in[5];
  const float* b2  = (const float*)d_in[6];
  const float* bl  = (const float*)d_in[7];
  const float* wf1 = (const float*)d_in[8];
  const float* wf2 = (const float*)d_in[9];
  const float* bf  = (const float*)d_in[10];
  float* out = (float*)d_out;

  float* ws = (float*)d_ws;
  float* rep = ws;                 // MAT
  float* g1  = ws + 1 * MAT;
  float* hsc = ws + 2 * MAT;       // E_h = 2^(head'*c1)
  float* dr  = ws + 3 * MAT;       // 2*MAT: float2 {E_d, rep}
  ushort* ub = (ushort*)(ws + 5 * MAT);
  ushort* xb    = ub + 0 * MAT;
  ushort* repb  = ub + 1 * MAT;
  ushort* attnb = ub + 2 * MAT;
  ushort* fcwt  = ub + 3 * MAT;
  ushort* w1t   = ub + 4 * MAT;
  ushort* w2t   = ub + 5 * MAT;
  ushort* wf1t  = ub + 6 * MAT;
  ushort* wf2t  = ub + 7 * MAT;

  k_conv<<<dim3(16, 16, 6), dim3(256), 0, stream>>>(x, fcw, w1, w2, wf1, wf2,
                                                    xb, fcwt, w1t, w2t, wf1t, wf2t);
  k_rep<<<dim3(128), dim3(512), 0, stream>>>(xb, fcwt, fcb, rep, repb, dr);
  k_triple<<<dim3(192), dim3(512), 0, stream>>>(repb, w1t, b1, w2t, b2, wf1t, bl,
                                                dr, hsc, g1);
  k_attn<<<dim3(128, 2), dim3(1024), 0, stream>>>(dr, hsc, attnb);
  k_final<<<dim3(128), dim3(512), 0, stream>>>(attnb, wf2t, g1, rep, bf, out);
}